// Round 1
// baseline (155.344 us; speedup 1.0000x reference)
//
#include <hip/hip_runtime.h>
#include <hip/hip_bf16.h>

// Reference analysis:
//   x1[b]   = relu(dot(inputs[b,:6400], W1) + b1)                  (scalar per row)
//   x[b,j]  = relu(x1[b]*W2[j] + b2[j])
//   seg3: only x[i*64, 1] for i in 0..63 is consumed:
//     h3[i] = relu(x[i*64,1]*W3a + b3a)
//     sel3[i*80+k] = relu(h3[i]*W3b[k] + b3b[k]), tiled 80x -> out[0 .. 409599]
//     out[t*5120 + i*80 + k] = sel3[i*80+k], t in 0..79
//   bias: out[409600 .. 409663] = 0
//   sel4: (b,col) pairs {(0,65),(682,69),(1365,67),(2048,65),(2730,69),(3413,67)}:
//     h4[i] = relu(x[b_i,col_i]*W4a + b4a)
//     out[409664 + i*513 + k] = relu(h4[i]*W4b[k] + b4b[k]), k in 0..512
// Total out = 412742 fp32.

__global__ __launch_bounds__(256) void hyper_pong_kernel(
    const float* __restrict__ inputs,
    const float* __restrict__ W1,  const float* __restrict__ b1,
    const float* __restrict__ W2,  const float* __restrict__ b2,
    const float* __restrict__ W3a, const float* __restrict__ b3a,
    const float* __restrict__ W3b, const float* __restrict__ b3b,
    const float* __restrict__ W4a, const float* __restrict__ b4a,
    const float* __restrict__ W4b, const float* __restrict__ b4b,
    float* __restrict__ out)
{
    const int blk = blockIdx.x;
    const int tid = threadIdx.x;
    const bool is3 = (blk < 64);

    // (batch, column) selection
    int b, col;
    if (is3) {
        b = blk * 64;
        col = 1;
    } else {
        const int bs[6] = {0, 682, 1365, 2048, 2730, 3413};
        const int cs[6] = {65, 69, 67, 65, 69, 67};
        b = bs[blk - 64];
        col = cs[blk - 64];
    }

    // ---- dot(inputs[b, :6400], W1) with 256 threads, float4 loads ----
    const float4* row = reinterpret_cast<const float4*>(inputs + (size_t)b * 6400);
    const float4* w   = reinterpret_cast<const float4*>(W1);
    float acc = 0.0f;
    #pragma unroll
    for (int i = tid; i < 1600; i += 256) {
        float4 r = row[i];
        float4 ww = w[i];
        acc += r.x * ww.x + r.y * ww.y + r.z * ww.z + r.w * ww.w;
    }
    // wave(64) shuffle reduction
    #pragma unroll
    for (int off = 32; off > 0; off >>= 1)
        acc += __shfl_down(acc, off);

    __shared__ float warp_sums[4];
    __shared__ float h_sh;
    const int lane = tid & 63;
    const int wv   = tid >> 6;
    if (lane == 0) warp_sums[wv] = acc;
    __syncthreads();

    if (tid == 0) {
        float dot = warp_sums[0] + warp_sums[1] + warp_sums[2] + warp_sums[3];
        float x1  = fmaxf(dot + b1[0], 0.0f);
        float xv  = fmaxf(x1 * W2[col] + b2[col], 0.0f);
        float h;
        if (is3) h = fmaxf(xv * W3a[0] + b3a[0], 0.0f);
        else     h = fmaxf(xv * W4a[0] + b4a[0], 0.0f);
        h_sh = h;
    }
    __syncthreads();
    const float h = h_sh;

    if (is3) {
        const int i = blk;
        // write 80 tiles x 80 values for this i
        for (int idx = tid; idx < 6400; idx += 256) {
            const int t = idx / 80;
            const int k = idx - t * 80;
            const float val = fmaxf(h * W3b[k] + b3b[k], 0.0f);
            out[(size_t)t * 5120 + (size_t)i * 80 + k] = val;
        }
        if (blk == 0 && tid < 64) {
            out[409600 + tid] = 0.0f;   // bias segment
        }
    } else {
        const int i = blk - 64;
        for (int k = tid; k < 513; k += 256) {
            const float val = fmaxf(h * W4b[k] + b4b[k], 0.0f);
            out[409664 + (size_t)i * 513 + k] = val;
        }
    }
}

extern "C" void kernel_launch(void* const* d_in, const int* in_sizes, int n_in,
                              void* d_out, int out_size, void* d_ws, size_t ws_size,
                              hipStream_t stream) {
    const float* inputs = (const float*)d_in[0];
    const float* W1  = (const float*)d_in[1];
    const float* b1  = (const float*)d_in[2];
    const float* W2  = (const float*)d_in[3];
    const float* b2  = (const float*)d_in[4];
    const float* W3a = (const float*)d_in[5];
    const float* b3a = (const float*)d_in[6];
    const float* W3b = (const float*)d_in[7];
    const float* b3b = (const float*)d_in[8];
    const float* W4a = (const float*)d_in[9];
    const float* b4a = (const float*)d_in[10];
    const float* W4b = (const float*)d_in[11];
    const float* b4b = (const float*)d_in[12];
    float* out = (float*)d_out;

    hipLaunchKernelGGL(hyper_pong_kernel, dim3(70), dim3(256), 0, stream,
                       inputs, W1, b1, W2, b2, W3a, b3a, W3b, b3b,
                       W4a, b4a, W4b, b4b, out);
}

// Round 2
// 153.233 us; speedup vs baseline: 1.0138x; 1.0138x over previous
//
#include <hip/hip_runtime.h>
#include <hip/hip_bf16.h>

// Reference analysis (verified round 1, absmax 0.0):
//   x1[b]   = relu(dot(inputs[b,:6400], W1) + b1)
//   x[b,j]  = relu(x1[b]*W2[j] + b2[j])
//   seg3: only x[i*64, 1], i in 0..63:
//     h3[i] = relu(x[i*64,1]*W3a + b3a)
//     val3[i][k] = relu(h3[i]*W3b[k] + b3b[k])   (k<80)
//     out[t*5120 + i*80 + k] = val3[i][k]  for t in 0..79   (tile 80x)
//   bias: out[409600..409663] = 0
//   sel4: (b,col) in {(0,65),(682,69),(1365,67),(2048,65),(2730,69),(3413,67)}:
//     h4[i] = relu(x[b,col]*W4a + b4a)
//     out[409664 + i*513 + k] = relu(h4[i]*W4b[k] + b4b[k])  (k<513)
// Total out = 412742 fp32 (~1.65 MB). Kernel is latency-bound (70 blocks);
// measured dur_us is dominated by harness reset fills (~140 us of 419 MB pokes).

__global__ __launch_bounds__(256) void hyper_pong_kernel(
    const float* __restrict__ inputs,
    const float* __restrict__ W1,  const float* __restrict__ b1,
    const float* __restrict__ W2,  const float* __restrict__ b2,
    const float* __restrict__ W3a, const float* __restrict__ b3a,
    const float* __restrict__ W3b, const float* __restrict__ b3b,
    const float* __restrict__ W4a, const float* __restrict__ b4a,
    const float* __restrict__ W4b, const float* __restrict__ b4b,
    float* __restrict__ out)
{
    const int blk = blockIdx.x;
    const int tid = threadIdx.x;
    const bool is3 = (blk < 64);

    int b, col;
    if (is3) {
        b = blk * 64;
        col = 1;
    } else {
        const int bs[6] = {0, 682, 1365, 2048, 2730, 3413};
        const int cs[6] = {65, 69, 67, 65, 69, 67};
        b = bs[blk - 64];
        col = cs[blk - 64];
    }

    // ---- issue small-weight loads early so they overlap the big dot ----
    float w3b_k = 0.0f, b3b_k = 0.0f;          // threads 0..79 (is3 blocks)
    float w4b_k[3] = {0, 0, 0}, b4b_k[3] = {0, 0, 0};  // 513 = 256+256+1
    if (is3) {
        if (tid < 80) { w3b_k = W3b[tid]; b3b_k = b3b[tid]; }
    } else {
        #pragma unroll
        for (int j = 0; j < 3; ++j) {
            const int k = tid + j * 256;
            if (k < 513) { w4b_k[j] = W4b[k]; b4b_k[j] = b4b[k]; }
        }
    }
    float s_b1 = 0, s_w2 = 0, s_b2 = 0, s_wa = 0, s_ba = 0;
    if (tid == 0) {
        s_b1 = b1[0];
        s_w2 = W2[col];
        s_b2 = b2[col];
        s_wa = is3 ? W3a[0] : W4a[0];
        s_ba = is3 ? b3a[0] : b4a[0];
    }

    // ---- dot(inputs[b, :6400], W1): 256 threads x float4 ----
    const float4* row = reinterpret_cast<const float4*>(inputs + (size_t)b * 6400);
    const float4* w   = reinterpret_cast<const float4*>(W1);
    float acc = 0.0f;
    #pragma unroll
    for (int i = tid; i < 1600; i += 256) {
        float4 r  = row[i];
        float4 ww = w[i];
        acc += r.x * ww.x + r.y * ww.y + r.z * ww.z + r.w * ww.w;
    }
    #pragma unroll
    for (int off = 32; off > 0; off >>= 1)
        acc += __shfl_down(acc, off);

    __shared__ float warp_sums[4];
    __shared__ float h_sh;
    if ((tid & 63) == 0) warp_sums[tid >> 6] = acc;
    __syncthreads();

    if (tid == 0) {
        float dot = warp_sums[0] + warp_sums[1] + warp_sums[2] + warp_sums[3];
        float x1  = fmaxf(dot + s_b1, 0.0f);
        float xv  = fmaxf(x1 * s_w2 + s_b2, 0.0f);
        h_sh = fmaxf(xv * s_wa + s_ba, 0.0f);
    }
    __syncthreads();
    const float h = h_sh;

    if (is3) {
        __shared__ float val_sh[80];
        if (tid < 80) val_sh[tid] = fmaxf(h * w3b_k + b3b_k, 0.0f);
        __syncthreads();

        const float4* val4 = reinterpret_cast<const float4*>(val_sh);
        float4* out4 = reinterpret_cast<float4*>(out);
        const int base = blk * 20;                 // (i*80)/4
        // 80 tiles x 20 float4 = 1600 vector stores per block
        #pragma unroll
        for (int idx = tid; idx < 1600; idx += 256) {
            const int t  = idx / 20;               // magic-mul, cheap
            const int k4 = idx - t * 20;
            out4[t * 1280 + base + k4] = val4[k4];
        }
        if (blk == 0 && tid < 16) {
            out4[102400 + tid] = make_float4(0.f, 0.f, 0.f, 0.f);  // bias seg
        }
    } else {
        const int i = blk - 64;
        #pragma unroll
        for (int j = 0; j < 3; ++j) {
            const int k = tid + j * 256;
            if (k < 513) {
                out[409664 + (size_t)i * 513 + k] =
                    fmaxf(h * w4b_k[j] + b4b_k[j], 0.0f);
            }
        }
    }
}

extern "C" void kernel_launch(void* const* d_in, const int* in_sizes, int n_in,
                              void* d_out, int out_size, void* d_ws, size_t ws_size,
                              hipStream_t stream) {
    const float* inputs = (const float*)d_in[0];
    const float* W1  = (const float*)d_in[1];
    const float* b1  = (const float*)d_in[2];
    const float* W2  = (const float*)d_in[3];
    const float* b2  = (const float*)d_in[4];
    const float* W3a = (const float*)d_in[5];
    const float* b3a = (const float*)d_in[6];
    const float* W3b = (const float*)d_in[7];
    const float* b3b = (const float*)d_in[8];
    const float* W4a = (const float*)d_in[9];
    const float* b4a = (const float*)d_in[10];
    const float* W4b = (const float*)d_in[11];
    const float* b4b = (const float*)d_in[12];
    float* out = (float*)d_out;

    hipLaunchKernelGGL(hyper_pong_kernel, dim3(70), dim3(256), 0, stream,
                       inputs, W1, b1, W2, b2, W3a, b3a, W3b, b3b,
                       W4a, b4a, W4b, b4b, out);
}